// Round 1
// baseline (899.025 us; speedup 1.0000x reference)
//
#include <hip/hip_runtime.h>
#include <hip/hip_bf16.h>
#include <stdint.h>

#define N_NODES 50000
#define N_EDGES 800000
#define IN_CH 256
#define HID 128
#define OUT_CH 64
#define EDGE_DIM 64

typedef __hip_bfloat16 bf16;
typedef __attribute__((ext_vector_type(8))) short short8;
typedef __attribute__((ext_vector_type(4))) float f32x4;

__device__ __forceinline__ void st_out(float* p, float v) { *p = v; }
__device__ __forceinline__ void st_out(bf16* p, float v) { *p = __float2bfloat16(v); }

// ---- one-shot weight prep: transpose + bf16 for all 5 weight matrices ----
// Wt[n*K + k] = bf16(W[k*N + n])
__device__ __forceinline__ void wt_one(const float* W, bf16* Wt, int K, int N, int i) {
    int n = i % N, k = i / N;
    Wt[n * K + k] = __float2bfloat16(W[i]);
}
__launch_bounds__(256)
__global__ void wt_prep_all(const float* W_in, const float* W_e, const float* W1,
                            const float* W2, const float* W_out,
                            bf16* Wt_in, bf16* Wt_e, bf16* Wt_1, bf16* Wt_2, bf16* Wt_out) {
    int i = blockIdx.x * 256 + threadIdx.x;
    if (i < 32768)       wt_one(W_in,  Wt_in,  256, 128, i);
    else if (i < 40960)  wt_one(W_e,   Wt_e,    64, 128, i - 32768);
    else if (i < 57344)  wt_one(W1,    Wt_1,   128, 128, i - 40960);
    else if (i < 73728)  wt_one(W2,    Wt_2,   128, 128, i - 57344);
    else if (i < 81920)  wt_one(W_out, Wt_out, 128,  64, i - 73728);
}

// MFMA GEMM: out[r, c] = act( A[row_src(r),:] @ W[:,c] + b[c] )
// A: InT [M x KTOT] row-major (fp32 converted at staging, bf16 copied).
// Wt: bf16 [N x KTOT] pre-transposed. 256 thr = 4 waves; MROWS-row block tile.
// GATHER: input row index indirected via gidx (permutation moved to READ side;
// output rows are always written sequentially / coalesced).
template<int KTOT, int N, int MROWS, bool RELU, bool GATHER, typename InT, typename OutT>
__launch_bounds__(256)
__global__ void gemm_mfma(const InT* __restrict__ A, const bf16* __restrict__ Wt,
                          const float* __restrict__ b, OutT* __restrict__ out,
                          int M, const int* __restrict__ gidx) {
    static_assert(KTOT % 64 == 0, "");
    constexpr int KC  = 64;
    constexpr int NCH = KTOT / KC;
    constexpr int KCP = KC + 8;            // 72: row = 144 B (16B-aligned, 2-way bank alias = free)
    constexpr int NT  = N / 16;
    constexpr int MT  = MROWS / 64;        // m-tiles per wave
    __shared__ __align__(16) bf16 Ws[N * KCP];
    __shared__ __align__(16) bf16 As[MROWS * KCP];

    const int tid  = threadIdx.x;
    const int wave = tid >> 6;
    const int lane = tid & 63;
    const int quad = lane >> 4;
    const int l16  = lane & 15;
    const int base = blockIdx.x * MROWS;

    f32x4 acc[MT][NT];
    #pragma unroll
    for (int m = 0; m < MT; m++)
        #pragma unroll
        for (int i = 0; i < NT; i++) acc[m][i] = (f32x4){0.f, 0.f, 0.f, 0.f};

    for (int ch = 0; ch < NCH; ch++) {
        const int kc = ch * KC;
        // stage weight chunk (bf16 16B copies)
        constexpr int WIT = N * KC / (256 * 8);
        #pragma unroll
        for (int it = 0; it < WIT; it++) {
            int t8 = (it * 256 + tid) * 8;
            int n = t8 / KC, k = t8 % KC;
            *(uint4*)&Ws[n * KCP + k] = *(const uint4*)&Wt[n * KTOT + kc + k];
        }
        // stage A chunk
        if constexpr (sizeof(InT) == 4) {
            constexpr int AIT = MROWS * KC / (256 * 4);
            #pragma unroll
            for (int it = 0; it < AIT; it++) {
                int t4 = (it * 256 + tid) * 4;
                int r = t4 / KC, k = t4 % KC;
                int gr = base + r;
                float4 v = make_float4(0.f, 0.f, 0.f, 0.f);
                if (gr < M) {
                    int ar = GATHER ? gidx[gr] : gr;
                    v = *(const float4*)&A[(size_t)ar * KTOT + kc + k];
                }
                *(__hip_bfloat162*)&As[r * KCP + k]     = __float22bfloat162_rn(make_float2(v.x, v.y));
                *(__hip_bfloat162*)&As[r * KCP + k + 2] = __float22bfloat162_rn(make_float2(v.z, v.w));
            }
        } else {
            constexpr int AIT = MROWS * KC / (256 * 8);
            #pragma unroll
            for (int it = 0; it < AIT; it++) {
                int t8 = (it * 256 + tid) * 8;
                int r = t8 / KC, k = t8 % KC;
                int gr = base + r;
                uint4 v = make_uint4(0u, 0u, 0u, 0u);
                if (gr < M) {
                    int ar = GATHER ? gidx[gr] : gr;
                    v = *(const uint4*)&A[(size_t)ar * KTOT + kc + k];
                }
                *(uint4*)&As[r * KCP + k] = v;
            }
        }
        __syncthreads();

        #pragma unroll
        for (int ks = 0; ks < KC / 32; ks++) {
            short8 af[MT];
            #pragma unroll
            for (int m = 0; m < MT; m++)
                af[m] = *(const short8*)&As[(wave * MT * 16 + m * 16 + l16) * KCP + ks * 32 + quad * 8];
            #pragma unroll
            for (int nt = 0; nt < NT; nt++) {
                short8 bfr = *(const short8*)&Ws[(nt * 16 + l16) * KCP + ks * 32 + quad * 8];
                #pragma unroll
                for (int m = 0; m < MT; m++)
                    acc[m][nt] = __builtin_amdgcn_mfma_f32_16x16x32_bf16(af[m], bfr, acc[m][nt], 0, 0, 0);
            }
        }
        __syncthreads();
    }

    // epilogue: C/D layout col=lane&15, row=quad*4+reg ; sequential coalesced rows
    #pragma unroll
    for (int m = 0; m < MT; m++) {
        const int r0 = base + wave * MT * 16 + m * 16 + quad * 4;
        #pragma unroll
        for (int reg = 0; reg < 4; reg++) {
            int gr = r0 + reg;
            if (gr < M) {
                #pragma unroll
                for (int nt = 0; nt < NT; nt++) {
                    int col = nt * 16 + l16;
                    float v = acc[m][nt][reg] + b[col];
                    if (RELU) v = fmaxf(v, 0.f);
                    st_out(&out[(size_t)gr * N + col], v);
                }
            }
        }
    }
}

// ---- counting sort of edges by dst ----
__launch_bounds__(256)
__global__ void hist_kernel(const int* __restrict__ ei, int* __restrict__ counts) {
    int edge = blockIdx.x * 256 + threadIdx.x;
    if (edge < N_EDGES) atomicAdd(&counts[ei[N_EDGES + edge]], 1);
}

__launch_bounds__(1024)
__global__ void scan_kernel(const int* __restrict__ counts, int* __restrict__ offsets,
                            int* __restrict__ cursor) {
    __shared__ int part[1024];
    const int tid = threadIdx.x;
    const int CH = (N_NODES + 1023) / 1024;
    int beg = tid * CH, end = min(beg + CH, N_NODES);
    int s = 0;
    for (int i = beg; i < end; i++) s += counts[i];
    part[tid] = s;
    __syncthreads();
    for (int off = 1; off < 1024; off <<= 1) {
        int t = (tid >= off) ? part[tid - off] : 0;
        __syncthreads();
        part[tid] += t;
        __syncthreads();
    }
    int run = (tid == 0) ? 0 : part[tid - 1];
    for (int i = beg; i < end; i++) {
        offsets[i] = run;
        cursor[i] = run;
        run += counts[i];
    }
    if (tid == 1023) offsets[N_NODES] = part[1023];
}

// esort[pos] = original edge id at sorted position pos (inverse perm, for gather)
__launch_bounds__(256)
__global__ void scatter_perm(const int* __restrict__ ei, int* __restrict__ cursor,
                             int* __restrict__ esort, int* __restrict__ src_sorted) {
    int edge = blockIdx.x * 256 + threadIdx.x;
    if (edge >= N_EDGES) return;
    int dst = ei[N_EDGES + edge];
    int pos = atomicAdd(&cursor[dst], 1);
    esort[pos] = edge;
    src_sorted[pos] = ei[edge];
}

// ---- segmented aggregation (all bf16): z[n] = h[n] + sum_{e->n} relu(h[src]+e) ----
// wave per node; 16 lanes per edge (8 ch/lane, 16B loads), 4 edges per step.
__device__ __forceinline__ float blo(uint32_t u) { return __uint_as_float(u << 16); }
__device__ __forceinline__ float bhi(uint32_t u) { return __uint_as_float(u & 0xffff0000u); }

__launch_bounds__(256)
__global__ void agg_kernel(const int* __restrict__ offsets, const int* __restrict__ src_sorted,
                           const bf16* __restrict__ e, const bf16* __restrict__ h,
                           bf16* __restrict__ z) {
    int wid = (blockIdx.x * 256 + threadIdx.x) >> 6;
    int lane = threadIdx.x & 63;
    if (wid >= N_NODES) return;
    const int beg = offsets[wid], end = offsets[wid + 1];
    const int q   = lane >> 4;       // which edge of the 4-edge group
    const int l16 = lane & 15;
    const int c8  = l16 * 8;         // 8 channels per lane

    float acc[8];
    #pragma unroll
    for (int j = 0; j < 8; j++) acc[j] = 0.f;

    for (int w = beg; w < end; w += 64) {
        const int cnt = min(64, end - w);
        int my_src = (w + lane < end) ? src_sorted[w + lane] : 0;
        for (int i = 0; i < cnt; i += 4) {
            bool ok = (i + q) < cnt;
            int s = __shfl(my_src, (i + q) & 63);
            uint4 ev = make_uint4(0u, 0u, 0u, 0u);
            uint4 hv = make_uint4(0u, 0u, 0u, 0u);
            if (ok) {
                // lanes 0..63 cover 4 consecutive e rows contiguously (1KB)
                ev = *(const uint4*)&e[(size_t)(w + i) * HID + lane * 8];
                hv = *(const uint4*)&h[(size_t)s * HID + c8];
            }
            uint32_t evs[4] = {ev.x, ev.y, ev.z, ev.w};
            uint32_t hvs[4] = {hv.x, hv.y, hv.z, hv.w};
            #pragma unroll
            for (int j = 0; j < 4; j++) {
                acc[2 * j]     += fmaxf(blo(evs[j]) + blo(hvs[j]), 0.f);
                acc[2 * j + 1] += fmaxf(bhi(evs[j]) + bhi(hvs[j]), 0.f);
            }
        }
    }
    // reduce the 4 edge-groups (lanes l16, l16+16, l16+32, l16+48)
    #pragma unroll
    for (int j = 0; j < 8; j++) {
        acc[j] += __shfl_xor(acc[j], 16);
        acc[j] += __shfl_xor(acc[j], 32);
    }
    if (lane < 16) {
        uint4 hs = *(const uint4*)&h[(size_t)wid * HID + c8];
        uint32_t hss[4] = {hs.x, hs.y, hs.z, hs.w};
        uint32_t o[4];
        #pragma unroll
        for (int j = 0; j < 4; j++) {
            float lo = acc[2 * j]     + blo(hss[j]);
            float hi = acc[2 * j + 1] + bhi(hss[j]);
            __hip_bfloat162 p = __float22bfloat162_rn(make_float2(lo, hi));
            o[j] = *(uint32_t*)&p;
        }
        *(uint4*)&z[(size_t)wid * HID + c8] = make_uint4(o[0], o[1], o[2], o[3]);
    }
}

extern "C" void kernel_launch(void* const* d_in, const int* in_sizes, int n_in,
                              void* d_out, int out_size, void* d_ws, size_t ws_size,
                              hipStream_t stream) {
    const float* x     = (const float*)d_in[0];
    const int*   ei    = (const int*)d_in[1];
    const float* ea    = (const float*)d_in[2];
    const float* W_in  = (const float*)d_in[3];
    const float* b_in  = (const float*)d_in[4];
    const float* W_e   = (const float*)d_in[5];
    const float* b_e   = (const float*)d_in[6];
    const float* W1    = (const float*)d_in[7];
    const float* b1    = (const float*)d_in[8];
    const float* W2    = (const float*)d_in[9];
    const float* b2    = (const float*)d_in[10];
    const float* W_out = (const float*)d_in[11];
    const float* b_out = (const float*)d_in[12];
    float* out = (float*)d_out;

    char* ws = (char*)d_ws;
    size_t off = 0;
    bf16*  h       = (bf16*) (ws + off); off += (size_t)N_NODES * HID * 2;     // 12.8 MB
    bf16*  z       = (bf16*) (ws + off); off += (size_t)N_NODES * HID * 2;     // 12.8 MB
    bf16*  e       = (bf16*) (ws + off); off += (size_t)N_EDGES * HID * 2;     // 204.8 MB
    int*   counts  = (int*)  (ws + off); off += (size_t)N_NODES * 4;
    int*   offsets = (int*)  (ws + off); off += (size_t)(N_NODES + 1) * 4;
    int*   cursor  = (int*)  (ws + off); off += (size_t)N_NODES * 4;
    int*   esort   = (int*)  (ws + off); off += (size_t)N_EDGES * 4;
    int*   srcs    = (int*)  (ws + off); off += (size_t)N_EDGES * 4;
    bf16*  Wt_in   = (bf16*) (ws + off); off += (size_t)HID * IN_CH * 2;
    bf16*  Wt_e    = (bf16*) (ws + off); off += (size_t)HID * EDGE_DIM * 2;
    bf16*  Wt_1    = (bf16*) (ws + off); off += (size_t)HID * HID * 2;
    bf16*  Wt_2    = (bf16*) (ws + off); off += (size_t)HID * HID * 2;
    bf16*  Wt_out  = (bf16*) (ws + off); off += (size_t)OUT_CH * HID * 2;

    // ---- weight prep (one kernel) ----
    wt_prep_all<<<(81920 + 255) / 256, 256, 0, stream>>>(
        W_in, W_e, W1, W2, W_out, Wt_in, Wt_e, Wt_1, Wt_2, Wt_out);

    // ---- counting sort by dst ----
    hipMemsetAsync(counts, 0, (size_t)N_NODES * 4, stream);
    hist_kernel<<<(N_EDGES + 255) / 256, 256, 0, stream>>>(ei, counts);
    scan_kernel<<<1, 1024, 0, stream>>>(counts, offsets, cursor);
    scatter_perm<<<(N_EDGES + 255) / 256, 256, 0, stream>>>(ei, cursor, esort, srcs);

    // h = x @ W_in + b_in   (fp32 in, bf16 out)
    gemm_mfma<IN_CH, HID, 64, false, false, float, bf16>
        <<<(N_NODES + 63) / 64, 256, 0, stream>>>(x, Wt_in, b_in, h, N_NODES, nullptr);

    // e[pos] = edge_attr[esort[pos]] @ W_e + b_e (gather-read, coalesced write)
    gemm_mfma<EDGE_DIM, HID, 128, false, true, float, bf16>
        <<<(N_EDGES + 127) / 128, 256, 0, stream>>>(ea, Wt_e, b_e, e, N_EDGES, esort);

    for (int layer = 0; layer < 3; ++layer) {
        agg_kernel<<<(N_NODES * 64 + 255) / 256, 256, 0, stream>>>(offsets, srcs, e, h, z);
        gemm_mfma<HID, HID, 64, true, false, bf16, bf16>
            <<<(N_NODES + 63) / 64, 256, 0, stream>>>(z, Wt_1, b1, h, N_NODES, nullptr);
        gemm_mfma<HID, HID, 64, true, false, bf16, bf16>
            <<<(N_NODES + 63) / 64, 256, 0, stream>>>(h, Wt_2, b2, z, N_NODES, nullptr);
        bf16* t = h; h = z; z = t;   // next layer's h is g2's output
    }

    // out = h @ W_out + b_out (fp32 out)
    gemm_mfma<HID, OUT_CH, 64, false, false, bf16, float>
        <<<(N_NODES + 63) / 64, 256, 0, stream>>>(h, Wt_out, b_out, out, N_NODES, nullptr);
}